// Round 3
// baseline (885.266 us; speedup 1.0000x reference)
//
#include <hip/hip_runtime.h>
#include <hip/hip_bf16.h>
#include <type_traits>

// Problem: PredicateLevelEncoder  B=32 T=64 N=36 VD=2048 H=512 S=300 Hc=256
// Device tensors are f32 (per reference dtypes); we convert MFMA operands to
// bf16 in workspace, accumulate f32, and write f32 outputs.

typedef __hip_bfloat16 bf16;
typedef unsigned int uint32;
typedef __attribute__((ext_vector_type(8))) short s8v;   // 8 bf16 = 4 VGPR
typedef __attribute__((ext_vector_type(4))) float f4v;   // mfma 16x16 accum

__device__ inline f4v mfma16(s8v a, s8v b, f4v c) {
    return __builtin_amdgcn_mfma_f32_16x16x32_bf16(a, b, c, 0, 0, 0);
}

__device__ inline float sigf(float x) {
    return __builtin_amdgcn_rcpf(1.f + __expf(-x));
}
__device__ inline float tanh_(float x) {
    // tanh(x) = 1 - 2/(exp(2x)+1); saturates correctly at +-inf
    return 1.f - 2.f * __builtin_amdgcn_rcpf(1.f + __expf(2.f * x));
}

// ---------------------------------------------------------------------------
// Fused f32 -> bf16 conversion, 9 jobs in one launch. Each block converts
// 1024 elements (all job sizes are multiples of 1024).
// ---------------------------------------------------------------------------
struct CvtJobs {
    const float* src[9];
    bf16*        dst[9];
    int          start[10];   // block range per job; start[9] = total blocks
};

__global__ __launch_bounds__(256) void cvt_kernel(CvtJobs jobs) {
    int blk = blockIdx.x;
    int j = 0;
#pragma unroll
    for (int i = 1; i < 9; ++i) if (blk >= jobs.start[i]) j = i;
    int off = (blk - jobs.start[j]) * 1024 + threadIdx.x * 4;
    float4 v = *(const float4*)(jobs.src[j] + off);
    union { bf16 h[4]; uint2 u; } p;
    p.h[0] = __float2bfloat16(v.x);
    p.h[1] = __float2bfloat16(v.y);
    p.h[2] = __float2bfloat16(v.z);
    p.h[3] = __float2bfloat16(v.w);
    *(uint2*)(jobs.dst[j] + off) = p.u;
}

// ---------------------------------------------------------------------------
// Generic GEMM:  C[M,N] = A[M,K](bf16,row-major) * W[N,K]^T + b1 + b2  (f32 b)
// One wave computes a 32x32 tile as 2x2 mfma_16x16x32 fragments, operands
// read directly from global (all matrices are L2/L3 resident at these sizes).
// permuteTB: row r=b*64+t is stored at row t*32+b (gates -> [T][B][4Hc]).
// ---------------------------------------------------------------------------
template <typename CT>
__global__ __launch_bounds__(256) void gemm_bt(
    const bf16* __restrict__ A, int lda,
    const bf16* __restrict__ W,
    const float* __restrict__ b1, const float* __restrict__ b2,
    CT* __restrict__ C, int ldc,
    int K, int tiles_n, int permuteTB)
{
    int w    = blockIdx.x * 4 + (threadIdx.x >> 6);
    int lane = threadIdx.x & 63;
    int mt = w / tiles_n, nt = w % tiles_n;
    int lo = lane & 15, hi = lane >> 4;

    const bf16* a0 = A + (size_t)(mt * 32 + lo) * lda + hi * 8;
    const bf16* a1 = a0 + (size_t)16 * lda;
    const bf16* w0 = W + (size_t)(nt * 32 + lo) * K + hi * 8;
    const bf16* w1 = w0 + (size_t)16 * K;

    f4v acc00 = {0.f,0.f,0.f,0.f}, acc01 = {0.f,0.f,0.f,0.f};
    f4v acc10 = {0.f,0.f,0.f,0.f}, acc11 = {0.f,0.f,0.f,0.f};

    for (int k = 0; k < K; k += 32) {
        s8v af0 = *(const s8v*)(a0 + k);
        s8v af1 = *(const s8v*)(a1 + k);
        s8v wf0 = *(const s8v*)(w0 + k);
        s8v wf1 = *(const s8v*)(w1 + k);
        acc00 = mfma16(af0, wf0, acc00);
        acc01 = mfma16(af0, wf1, acc01);
        acc10 = mfma16(af1, wf0, acc10);
        acc11 = mfma16(af1, wf1, acc11);
    }

    int c0 = nt * 32 + lo, c1 = c0 + 16;
    float bv0 = b1 ? b1[c0] : 0.f;
    float bv1 = b1 ? b1[c1] : 0.f;
    if (b2) { bv0 += b2[c0]; bv1 += b2[c1]; }

    int r0 = mt * 32 + hi * 4;
#pragma unroll
    for (int i = 0; i < 4; ++i) {
        int ra = r0 + i;
        int rb = ra + 16;
        int rra = permuteTB ? ((ra & 63) * 32 + (ra >> 6)) : ra;
        int rrb = permuteTB ? ((rb & 63) * 32 + (rb >> 6)) : rb;
        float v;
        v = acc00[i] + bv0;
        if constexpr (std::is_same<CT, float>::value) C[(size_t)rra * ldc + c0] = v;
        else C[(size_t)rra * ldc + c0] = __float2bfloat16(v);
        v = acc01[i] + bv1;
        if constexpr (std::is_same<CT, float>::value) C[(size_t)rra * ldc + c1] = v;
        else C[(size_t)rra * ldc + c1] = __float2bfloat16(v);
        v = acc10[i] + bv0;
        if constexpr (std::is_same<CT, float>::value) C[(size_t)rrb * ldc + c0] = v;
        else C[(size_t)rrb * ldc + c0] = __float2bfloat16(v);
        v = acc11[i] + bv1;
        if constexpr (std::is_same<CT, float>::value) C[(size_t)rrb * ldc + c1] = v;
        else C[(size_t)rrb * ldc + c1] = __float2bfloat16(v);
    }
}

// ---------------------------------------------------------------------------
// Fused additive attention for one (b,t): scores -> softmax_N -> weighted sum.
// Uo already contains U_b + b_attn.  attn_obj = Wf + sum_n aw[n]*Uo[b,n,:]
// (softmax weights sum to 1, so Wf+bias factor out of the weighted sum).
// Writes feats[bt][512..1023] (bf16).
// ---------------------------------------------------------------------------
__global__ __launch_bounds__(256) void attn_kernel(
    const float* __restrict__ Wf,   // [2048][512]
    const float* __restrict__ Uo,   // [32][36][512]
    const float* __restrict__ wW,   // [512]
    const float* __restrict__ wB,   // [1]
    bf16* __restrict__ feats)       // [2048][1024]
{
    int bt = blockIdx.x, b = bt >> 6;
    int wv = threadIdx.x >> 6, lane = threadIdx.x & 63;
    __shared__ float s_aw[36];

    float wfr[8], wr[8];
    const float* wfrow = Wf + (size_t)bt * 512 + lane * 8;
#pragma unroll
    for (int i = 0; i < 8; ++i) {
        wfr[i] = wfrow[i];
        wr[i]  = wW[lane * 8 + i];
    }
    float wbv = wB[0];

    for (int n = wv; n < 36; n += 4) {
        const float* uo = Uo + ((size_t)b * 36 + n) * 512 + lane * 8;
        float s = 0.f;
#pragma unroll
        for (int i = 0; i < 8; ++i) s += wr[i] * tanh_(wfr[i] + uo[i]);
#pragma unroll
        for (int off = 32; off; off >>= 1) s += __shfl_xor(s, off);
        if (lane == 0) s_aw[n] = s + wbv;
    }
    __syncthreads();
    if (threadIdx.x == 0) {
        float mx = -1e30f;
#pragma unroll
        for (int n = 0; n < 36; ++n) mx = fmaxf(mx, s_aw[n]);
        float e[36], sum = 0.f;
#pragma unroll
        for (int n = 0; n < 36; ++n) { e[n] = __expf(s_aw[n] - mx); sum += e[n]; }
        float r = __builtin_amdgcn_rcpf(sum);
#pragma unroll
        for (int n = 0; n < 36; ++n) s_aw[n] = e[n] * r;
    }
    __syncthreads();

    int h0 = threadIdx.x * 2;
    const float* wf2 = Wf + (size_t)bt * 512 + h0;
    float a0 = wf2[0], a1 = wf2[1];
    for (int n = 0; n < 36; ++n) {
        float awn = s_aw[n];
        const float* uo = Uo + ((size_t)b * 36 + n) * 512 + h0;
        a0 += awn * uo[0];
        a1 += awn * uo[1];
    }
    feats[(size_t)bt * 1024 + 512 + h0]     = __float2bfloat16(a0);
    feats[(size_t)bt * 1024 + 512 + h0 + 1] = __float2bfloat16(a1);
}

// ---------------------------------------------------------------------------
// BiLSTM recurrent part. 8 blocks: blocks 0-3 forward, 4-7 backward; each
// block owns 64 gate-columns (j-slice) for ALL 32 batches. Whh slice lives in
// registers as pre-formed mfma B-fragments (4 gates x 8 k-tiles = 128 VGPR).
//
// h exchange: coherent-data design. h values are stored/loaded as RELAXED
// agent-scope atomics (u32 = 2 packed bf16) which bypass L1/L2 to the
// coherence point -- so NO acquire/release fences (buffer_inv / buffer_wbl2)
// are needed anywhere in the loop, and the per-XCD L2 stays warm for the
// gate inputs and Whh. Phase flag is a relaxed atomic counter; ordering is
// provided by __syncthreads() (drains vmcnt before s_barrier).
// ---------------------------------------------------------------------------
__device__ inline void grid_bar(int* bar, int target) {
    __syncthreads();   // all waves' coherent stores drained (vmcnt 0) + joined
    if (threadIdx.x == 0) {
        __hip_atomic_fetch_add(bar, 1, __ATOMIC_RELAXED, __HIP_MEMORY_SCOPE_AGENT);
        while (__hip_atomic_load(bar, __ATOMIC_RELAXED, __HIP_MEMORY_SCOPE_AGENT) < target) {}
    }
    __syncthreads();
}

__global__ __launch_bounds__(256, 1) void lstm_kernel(
    const bf16* __restrict__ WhhF, const bf16* __restrict__ WhhB, // [1024][256] bf16
    const float* __restrict__ gatesF, const float* __restrict__ gatesB, // [64][32][1024] f32
    uint32* __restrict__ hx,  // [2 dir][2 slot][32][128] u32 (2 packed bf16)
    float* __restrict__ out,  // [32][64][512] f32
    int* __restrict__ bar)
{
    int bi  = blockIdx.x;
    int dir = bi >> 2;
    int jb  = (bi & 3) * 64;
    int wv = threadIdx.x >> 6, lane = threadIdx.x & 63;
    int lo = lane & 15, hi = lane >> 4;

    const bf16*  Whh   = dir ? WhhB : WhhF;
    const float* gates = dir ? gatesB : gatesF;
    uint32* hxd  = hx + (size_t)dir * 2 * 32 * 128;
    int* mybar = bar + dir * 16;
    int j0 = jb + wv * 16;

    // Whh B-fragments, resident for the whole kernel.
    s8v whhF[4][8];
#pragma unroll
    for (int g = 0; g < 4; ++g)
#pragma unroll
        for (int kt = 0; kt < 8; ++kt)
            whhF[g][kt] = *(const s8v*)(Whh + (size_t)(g * 256 + j0 + lo) * 256 + kt * 32 + hi * 8);

    // zero h slot 0 (this block's j-slice = 32 u32-words per batch row)
    for (int x = threadIdx.x; x < 1024; x += 256) {
        int b = x >> 5, jw = (jb >> 1) + (x & 31);
        __hip_atomic_store(&hxd[b * 128 + jw], 0u, __ATOMIC_RELAXED, __HIP_MEMORY_SCOPE_AGENT);
    }

    float cst[2][4] = {{0.f,0.f,0.f,0.f},{0.f,0.f,0.f,0.f}};
    int phase = 0;
    grid_bar(mybar, 4 * (++phase));

    for (int t = 0; t < 64; ++t) {
        const uint32* hr = hxd + (t & 1) * (32 * 128);
        uint32*       hw = hxd + ((t & 1) ^ 1) * (32 * 128);
        int tp = dir ? (63 - t) : t;
        const float* gin = gates + (size_t)tp * 32 * 1024;

        // per-lane gate inputs (precomputed x-projection + biases, f32, L2-warm)
        float gv[2][4][4];
#pragma unroll
        for (int m = 0; m < 2; ++m)
#pragma unroll
            for (int i = 0; i < 4; ++i) {
                int b = m * 16 + hi * 4 + i;
#pragma unroll
                for (int g = 0; g < 4; ++g)
                    gv[m][g][i] = gin[(size_t)b * 1024 + g * 256 + j0 + lo];
            }

        // h A-fragments via coherent (agent-scope relaxed) dword loads
        s8v aF[2][8];
#pragma unroll
        for (int m = 0; m < 2; ++m)
#pragma unroll
            for (int kt = 0; kt < 8; ++kt) {
                union { uint32 u[4]; s8v v; } tt;
                int base = (m * 16 + lo) * 128 + kt * 16 + hi * 4;
#pragma unroll
                for (int q = 0; q < 4; ++q)
                    tt.u[q] = __hip_atomic_load(&hr[base + q], __ATOMIC_RELAXED,
                                                __HIP_MEMORY_SCOPE_AGENT);
                aF[m][kt] = tt.v;
            }

        f4v acc[2][4];
#pragma unroll
        for (int m = 0; m < 2; ++m)
#pragma unroll
            for (int g = 0; g < 4; ++g) acc[m][g] = (f4v){0.f,0.f,0.f,0.f};
#pragma unroll
        for (int kt = 0; kt < 8; ++kt)
#pragma unroll
            for (int m = 0; m < 2; ++m)
#pragma unroll
                for (int g = 0; g < 4; ++g)
                    acc[m][g] = mfma16(aF[m][kt], whhF[g][kt], acc[m][g]);

        float hv[2][4];
#pragma unroll
        for (int m = 0; m < 2; ++m)
#pragma unroll
            for (int i = 0; i < 4; ++i) {
                float xi = acc[m][0][i] + gv[m][0][i];
                float xf = acc[m][1][i] + gv[m][1][i];
                float xg = acc[m][2][i] + gv[m][2][i];
                float xo = acc[m][3][i] + gv[m][3][i];
                float c = sigf(xf) * cst[m][i] + sigf(xi) * tanh_(xg);
                cst[m][i] = c;
                float h = sigf(xo) * tanh_(c);
                hv[m][i] = h;
                int b = m * 16 + hi * 4 + i;
                out[((size_t)b * 64 + tp) * 512 + dir * 256 + j0 + lo] = h;
            }

        // pack bf16 pairs across lane-neighbors; even lanes store the dword
#pragma unroll
        for (int m = 0; m < 2; ++m)
#pragma unroll
            for (int i = 0; i < 4; ++i) {
                float o2 = __shfl_xor(hv[m][i], 1);
                if (!(lane & 1)) {
                    uint32 p = (uint32)__bfloat16_as_ushort(__float2bfloat16(hv[m][i]))
                             | ((uint32)__bfloat16_as_ushort(__float2bfloat16(o2)) << 16);
                    int b = m * 16 + hi * 4 + i;
                    __hip_atomic_store(&hw[b * 128 + ((j0 + lo) >> 1)], p,
                                       __ATOMIC_RELAXED, __HIP_MEMORY_SCOPE_AGENT);
                }
            }

        grid_bar(mybar, 4 * (++phase));
    }
}

// ---------------------------------------------------------------------------
// action = max over T of output; action_semantics = action @ fc_W^T + fc_b
// ---------------------------------------------------------------------------
__global__ __launch_bounds__(256) void final_kernel(
    const float* __restrict__ out,   // [32][64][512]
    const float* __restrict__ fcW,   // [300][512]
    const float* __restrict__ fcb,   // [300]
    float* __restrict__ osem)        // [32][300]
{
    int b = blockIdx.x, tid = threadIdx.x;
    __shared__ float act[512];
    for (int h = tid; h < 512; h += 256) {
        float m = -1e30f;
        const float* p = out + (size_t)b * 64 * 512 + h;
#pragma unroll 8
        for (int t = 0; t < 64; ++t) m = fmaxf(m, p[t * 512]);
        act[h] = m;
    }
    __syncthreads();
    int wv = tid >> 6, lane = tid & 63;
    for (int s = wv; s < 300; s += 4) {
        const float* wrow = fcW + (size_t)s * 512 + lane * 8;
        float a = 0.f;
#pragma unroll
        for (int i = 0; i < 8; ++i) a += act[lane * 8 + i] * wrow[i];
#pragma unroll
        for (int off = 32; off; off >>= 1) a += __shfl_xor(a, off);
        if (lane == 0) osem[b * 300 + s] = a + fcb[s];
    }
}

// ---------------------------------------------------------------------------
extern "C" void kernel_launch(void* const* d_in, const int* in_sizes, int n_in,
                              void* d_out, int out_size, void* d_ws, size_t ws_size,
                              hipStream_t stream)
{
    const float* visual  = (const float*)d_in[0];
    const float* objects = (const float*)d_in[1];
    const float* lin_W   = (const float*)d_in[2];
    const float* lin_b   = (const float*)d_in[3];
    const float* W_W     = (const float*)d_in[4];
    const float* W_b     = (const float*)d_in[5];
    const float* U_W     = (const float*)d_in[6];
    const float* U_b     = (const float*)d_in[7];
    const float* b_attn  = (const float*)d_in[8];
    const float* w_W     = (const float*)d_in[9];
    const float* w_b     = (const float*)d_in[10];
    const float* Wih_f   = (const float*)d_in[11];
    const float* Whh_f   = (const float*)d_in[12];
    const float* bih_f   = (const float*)d_in[13];
    const float* bhh_f   = (const float*)d_in[14];
    const float* Wih_b   = (const float*)d_in[15];
    const float* Whh_b   = (const float*)d_in[16];
    const float* bih_b   = (const float*)d_in[17];
    const float* bhh_b   = (const float*)d_in[18];
    const float* fc_W    = (const float*)d_in[19];
    const float* fc_b    = (const float*)d_in[20];

    char* ws = (char*)d_ws;
    size_t o = 0;
    bf16*   feats   = (bf16*)(ws + o);   o += (size_t)2048 * 1024 * 2;   // [BT][1024] bf16
    float*  Wf      = (float*)(ws + o);  o += (size_t)2048 * 512 * 4;    // [BT][512] f32
    float*  Uo      = (float*)(ws + o);  o += (size_t)1152 * 512 * 4;    // [B*36][512] f32
    float*  gatesF  = (float*)(ws + o);  o += (size_t)2048 * 1024 * 4;   // [T][B][1024] f32
    float*  gatesB  = (float*)(ws + o);  o += (size_t)2048 * 1024 * 4;
    uint32* hx      = (uint32*)(ws + o); o += (size_t)2 * 2 * 32 * 128 * 4;
    int*    bar     = (int*)(ws + o);    o += 256;
    bf16*  visual_b  = (bf16*)(ws + o); o += (size_t)4194304 * 2;
    bf16*  objects_b = (bf16*)(ws + o); o += (size_t)589824 * 2;
    bf16*  lin_Wb    = (bf16*)(ws + o); o += (size_t)1048576 * 2;
    bf16*  W_Wb      = (bf16*)(ws + o); o += (size_t)262144 * 2;
    bf16*  U_Wb      = (bf16*)(ws + o); o += (size_t)262144 * 2;
    bf16*  Wih_fb    = (bf16*)(ws + o); o += (size_t)1048576 * 2;
    bf16*  Whh_fb    = (bf16*)(ws + o); o += (size_t)262144 * 2;
    bf16*  Wih_bb    = (bf16*)(ws + o); o += (size_t)1048576 * 2;
    bf16*  Whh_bb    = (bf16*)(ws + o); o += (size_t)262144 * 2;

    hipMemsetAsync(bar, 0, 256, stream);

    // fused f32->bf16 conversion (all sizes are multiples of 1024)
    CvtJobs cj;
    const float* srcs[9] = {visual, objects, lin_W, W_W, U_W, Wih_f, Whh_f, Wih_b, Whh_b};
    bf16* dsts[9] = {visual_b, objects_b, lin_Wb, W_Wb, U_Wb, Wih_fb, Whh_fb, Wih_bb, Whh_bb};
    int ns[9] = {4194304, 589824, 1048576, 262144, 262144, 1048576, 262144, 1048576, 262144};
    int acc_b = 0;
    for (int i = 0; i < 9; ++i) {
        cj.src[i] = srcs[i];
        cj.dst[i] = dsts[i];
        cj.start[i] = acc_b;
        acc_b += ns[i] / 1024;
    }
    cj.start[9] = acc_b;

    dim3 blk(256);
    cvt_kernel<<<acc_b, blk, 0, stream>>>(cj);

    // f3d -> feats[:, :512]   (M=2048,N=512,K=2048)
    gemm_bt<bf16><<<256, blk, 0, stream>>>(visual_b, 2048, lin_Wb, lin_b, nullptr,
                                           feats, 1024, 2048, 16, 0);
    // Uo' = objects@U_W^T + (U_b + b_attn)   (M=1152,N=512,K=512)
    gemm_bt<float><<<144, blk, 0, stream>>>(objects_b, 512, U_Wb, U_b, b_attn,
                                            Uo, 512, 512, 16, 0);
    // Wf = f3d@W_W^T + W_b   (M=2048,N=512,K=512)
    gemm_bt<float><<<256, blk, 0, stream>>>(feats, 1024, W_Wb, W_b, nullptr,
                                            Wf, 512, 512, 16, 0);
    // fused attention -> feats[:, 512:]
    attn_kernel<<<2048, blk, 0, stream>>>(Wf, Uo, w_W, w_b, feats);
    // gate input projections -> [T][B][1024] f32   (M=2048,N=1024,K=1024)
    gemm_bt<float><<<512, blk, 0, stream>>>(feats, 1024, Wih_fb, bih_f, bhh_f,
                                            gatesF, 1024, 1024, 32, 1);
    gemm_bt<float><<<512, blk, 0, stream>>>(feats, 1024, Wih_bb, bih_b, bhh_b,
                                            gatesB, 1024, 1024, 32, 1);
    // recurrent BiLSTM -> d_out[0 .. 1048575]
    lstm_kernel<<<8, blk, 0, stream>>>(Whh_fb, Whh_bb, gatesF, gatesB, hx,
                                       (float*)d_out, bar);
    // action max + fc -> d_out[1048576 ..]
    final_kernel<<<32, blk, 0, stream>>>((float*)d_out, fc_W, fc_b,
                                         (float*)d_out + 1048576);
}

// Round 4
// 599.207 us; speedup vs baseline: 1.4774x; 1.4774x over previous
//
#include <hip/hip_runtime.h>
#include <hip/hip_bf16.h>
#include <type_traits>

// Problem: PredicateLevelEncoder  B=32 T=64 N=36 VD=2048 H=512 S=300 Hc=256
// Device tensors are f32 (per reference dtypes); we convert MFMA operands to
// bf16 in workspace, accumulate f32, and write f32 outputs.

typedef __hip_bfloat16 bf16;
typedef unsigned int uint32;
typedef __attribute__((ext_vector_type(8))) short s8v;   // 8 bf16 = 4 VGPR
typedef __attribute__((ext_vector_type(4))) float f4v;   // mfma 16x16 accum

__device__ inline f4v mfma16(s8v a, s8v b, f4v c) {
    return __builtin_amdgcn_mfma_f32_16x16x32_bf16(a, b, c, 0, 0, 0);
}

__device__ inline float sigf(float x) {
    return __builtin_amdgcn_rcpf(1.f + __expf(-x));
}
__device__ inline float tanh_(float x) {
    // tanh(x) = 1 - 2/(exp(2x)+1); saturates correctly at +-inf
    return 1.f - 2.f * __builtin_amdgcn_rcpf(1.f + __expf(2.f * x));
}

// ---------------------------------------------------------------------------
// Fused f32 -> bf16 conversion, 9 jobs in one launch. Each block converts
// 1024 elements (all job sizes are multiples of 1024).
// ---------------------------------------------------------------------------
struct CvtJobs {
    const float* src[9];
    bf16*        dst[9];
    int          start[10];   // block range per job; start[9] = total blocks
};

__global__ __launch_bounds__(256) void cvt_kernel(CvtJobs jobs) {
    int blk = blockIdx.x;
    int j = 0;
#pragma unroll
    for (int i = 1; i < 9; ++i) if (blk >= jobs.start[i]) j = i;
    int off = (blk - jobs.start[j]) * 1024 + threadIdx.x * 4;
    float4 v = *(const float4*)(jobs.src[j] + off);
    union { bf16 h[4]; uint2 u; } p;
    p.h[0] = __float2bfloat16(v.x);
    p.h[1] = __float2bfloat16(v.y);
    p.h[2] = __float2bfloat16(v.z);
    p.h[3] = __float2bfloat16(v.w);
    *(uint2*)(jobs.dst[j] + off) = p.u;
}

// ---------------------------------------------------------------------------
// Generic GEMM:  C[M,N] = A[M,K](bf16,row-major) * W[N,K]^T + b1 + b2  (f32 b)
// One wave computes a 32x32 tile as 2x2 mfma_16x16x32 fragments, operands
// read directly from global (all matrices are L2/L3 resident at these sizes).
// permuteTB: row r=b*64+t is stored at row t*32+b (gates -> [T][B][4Hc]).
// ---------------------------------------------------------------------------
template <typename CT>
__global__ __launch_bounds__(256) void gemm_bt(
    const bf16* __restrict__ A, int lda,
    const bf16* __restrict__ W,
    const float* __restrict__ b1, const float* __restrict__ b2,
    CT* __restrict__ C, int ldc,
    int K, int tiles_n, int permuteTB)
{
    int w    = blockIdx.x * 4 + (threadIdx.x >> 6);
    int lane = threadIdx.x & 63;
    int mt = w / tiles_n, nt = w % tiles_n;
    int lo = lane & 15, hi = lane >> 4;

    const bf16* a0 = A + (size_t)(mt * 32 + lo) * lda + hi * 8;
    const bf16* a1 = a0 + (size_t)16 * lda;
    const bf16* w0 = W + (size_t)(nt * 32 + lo) * K + hi * 8;
    const bf16* w1 = w0 + (size_t)16 * K;

    f4v acc00 = {0.f,0.f,0.f,0.f}, acc01 = {0.f,0.f,0.f,0.f};
    f4v acc10 = {0.f,0.f,0.f,0.f}, acc11 = {0.f,0.f,0.f,0.f};

    for (int k = 0; k < K; k += 32) {
        s8v af0 = *(const s8v*)(a0 + k);
        s8v af1 = *(const s8v*)(a1 + k);
        s8v wf0 = *(const s8v*)(w0 + k);
        s8v wf1 = *(const s8v*)(w1 + k);
        acc00 = mfma16(af0, wf0, acc00);
        acc01 = mfma16(af0, wf1, acc01);
        acc10 = mfma16(af1, wf0, acc10);
        acc11 = mfma16(af1, wf1, acc11);
    }

    int c0 = nt * 32 + lo, c1 = c0 + 16;
    float bv0 = b1 ? b1[c0] : 0.f;
    float bv1 = b1 ? b1[c1] : 0.f;
    if (b2) { bv0 += b2[c0]; bv1 += b2[c1]; }

    int r0 = mt * 32 + hi * 4;
#pragma unroll
    for (int i = 0; i < 4; ++i) {
        int ra = r0 + i;
        int rb = ra + 16;
        int rra = permuteTB ? ((ra & 63) * 32 + (ra >> 6)) : ra;
        int rrb = permuteTB ? ((rb & 63) * 32 + (rb >> 6)) : rb;
        float v;
        v = acc00[i] + bv0;
        if constexpr (std::is_same<CT, float>::value) C[(size_t)rra * ldc + c0] = v;
        else C[(size_t)rra * ldc + c0] = __float2bfloat16(v);
        v = acc01[i] + bv1;
        if constexpr (std::is_same<CT, float>::value) C[(size_t)rra * ldc + c1] = v;
        else C[(size_t)rra * ldc + c1] = __float2bfloat16(v);
        v = acc10[i] + bv0;
        if constexpr (std::is_same<CT, float>::value) C[(size_t)rrb * ldc + c0] = v;
        else C[(size_t)rrb * ldc + c0] = __float2bfloat16(v);
        v = acc11[i] + bv1;
        if constexpr (std::is_same<CT, float>::value) C[(size_t)rrb * ldc + c1] = v;
        else C[(size_t)rrb * ldc + c1] = __float2bfloat16(v);
    }
}

// ---------------------------------------------------------------------------
// Fused additive attention for one (b,t): scores -> softmax_N -> weighted sum.
// Uo already contains U_b + b_attn.  attn_obj = Wf + sum_n aw[n]*Uo[b,n,:]
// (softmax weights sum to 1, so Wf+bias factor out of the weighted sum).
// Writes feats[bt][512..1023] (bf16).
// ---------------------------------------------------------------------------
__global__ __launch_bounds__(256) void attn_kernel(
    const float* __restrict__ Wf,   // [2048][512]
    const float* __restrict__ Uo,   // [32][36][512]
    const float* __restrict__ wW,   // [512]
    const float* __restrict__ wB,   // [1]
    bf16* __restrict__ feats)       // [2048][1024]
{
    int bt = blockIdx.x, b = bt >> 6;
    int wv = threadIdx.x >> 6, lane = threadIdx.x & 63;
    __shared__ float s_aw[36];

    float wfr[8], wr[8];
    const float* wfrow = Wf + (size_t)bt * 512 + lane * 8;
#pragma unroll
    for (int i = 0; i < 8; ++i) {
        wfr[i] = wfrow[i];
        wr[i]  = wW[lane * 8 + i];
    }
    float wbv = wB[0];

    for (int n = wv; n < 36; n += 4) {
        const float* uo = Uo + ((size_t)b * 36 + n) * 512 + lane * 8;
        float s = 0.f;
#pragma unroll
        for (int i = 0; i < 8; ++i) s += wr[i] * tanh_(wfr[i] + uo[i]);
#pragma unroll
        for (int off = 32; off; off >>= 1) s += __shfl_xor(s, off);
        if (lane == 0) s_aw[n] = s + wbv;
    }
    __syncthreads();
    if (threadIdx.x == 0) {
        float mx = -1e30f;
#pragma unroll
        for (int n = 0; n < 36; ++n) mx = fmaxf(mx, s_aw[n]);
        float e[36], sum = 0.f;
#pragma unroll
        for (int n = 0; n < 36; ++n) { e[n] = __expf(s_aw[n] - mx); sum += e[n]; }
        float r = __builtin_amdgcn_rcpf(sum);
#pragma unroll
        for (int n = 0; n < 36; ++n) s_aw[n] = e[n] * r;
    }
    __syncthreads();

    int h0 = threadIdx.x * 2;
    const float* wf2 = Wf + (size_t)bt * 512 + h0;
    float a0 = wf2[0], a1 = wf2[1];
    for (int n = 0; n < 36; ++n) {
        float awn = s_aw[n];
        const float* uo = Uo + ((size_t)b * 36 + n) * 512 + h0;
        a0 += awn * uo[0];
        a1 += awn * uo[1];
    }
    feats[(size_t)bt * 1024 + 512 + h0]     = __float2bfloat16(a0);
    feats[(size_t)bt * 1024 + 512 + h0 + 1] = __float2bfloat16(a1);
}

// ---------------------------------------------------------------------------
// BiLSTM recurrent part. 8 blocks: blocks 0-3 forward, 4-7 backward; each
// block owns 64 gate-columns (j-slice) for ALL 32 batches. Whh slice lives in
// registers as pre-formed mfma B-fragments (4 gates x 8 k-tiles = 128 VGPR).
//
// Synchronization redesign (R3 post-mortem):
//  - h values: stored with relaxed agent-scope atomic dword stores (packed
//    2xbf16) -> land at the coherence point; LOADED with one inline-asm batch
//    of 16 pipelined global_load_dwordx4 sc1 + a single s_waitcnt INSIDE the
//    asm (R3's per-atomic-load serialization was the regression).
//  - barrier: per-block monotonic flag on its own cacheline (no RMW line
//    bouncing); all threads poll with s_sleep backoff. No acquire/release
//    anywhere -> no buffer_inv / buffer_wbl2, L2 stays warm for gates.
//  - gate loads for step t are issued BEFORE the poll (independent of h).
// ---------------------------------------------------------------------------
__global__ __launch_bounds__(256, 1) void lstm_kernel(
    const bf16* __restrict__ WhhF, const bf16* __restrict__ WhhB, // [1024][256] bf16
    const float* __restrict__ gatesF, const float* __restrict__ gatesB, // [64][32][1024] f32
    uint32* __restrict__ hx,  // [2 dir][2 slot][32][128] u32 (2 packed bf16)
    float* __restrict__ out,  // [32][64][512] f32
    int* __restrict__ bar)    // flags: [(dir*4+peer)*16]
{
    int bi  = blockIdx.x;
    int dir = bi >> 2;
    int pid = bi & 3;
    int jb  = pid * 64;
    int wv = threadIdx.x >> 6, lane = threadIdx.x & 63;
    int lo = lane & 15, hi = lane >> 4;

    const bf16*  Whh   = dir ? WhhB : WhhF;
    const float* gates = dir ? gatesB : gatesF;
    uint32* hxd  = hx + (size_t)dir * 2 * 32 * 128;
    int j0 = jb + wv * 16;

    // Whh B-fragments, resident for the whole kernel.
    s8v whhF[4][8];
#pragma unroll
    for (int g = 0; g < 4; ++g)
#pragma unroll
        for (int kt = 0; kt < 8; ++kt)
            whhF[g][kt] = *(const s8v*)(Whh + (size_t)(g * 256 + j0 + lo) * 256 + kt * 32 + hi * 8);

    // zero h slot 0 (this block's j-slice = 32 u32-words per batch row)
    for (int x = threadIdx.x; x < 1024; x += 256) {
        int b = x >> 5, jw = (jb >> 1) + (x & 31);
        __hip_atomic_store(&hxd[b * 128 + jw], 0u, __ATOMIC_RELAXED, __HIP_MEMORY_SCOPE_AGENT);
    }
    __syncthreads();   // drains the zeroing stores (vmcnt 0 before s_barrier)
    if (threadIdx.x == 0)
        __hip_atomic_store(&bar[(dir * 4 + pid) * 16], 1, __ATOMIC_RELAXED,
                           __HIP_MEMORY_SCOPE_AGENT);

    float cst[2][4] = {{0.f,0.f,0.f,0.f},{0.f,0.f,0.f,0.f}};

    for (int t = 0; t < 64; ++t) {
        const uint32* hr = hxd + (t & 1) * (32 * 128);
        uint32*       hw = hxd + ((t & 1) ^ 1) * (32 * 128);
        int tp = dir ? (63 - t) : t;
        const float* gin = gates + (size_t)tp * 32 * 1024;

        // gate inputs for this step -- independent of h, issue BEFORE poll
        float gv[2][4][4];
#pragma unroll
        for (int m = 0; m < 2; ++m)
#pragma unroll
            for (int i = 0; i < 4; ++i) {
                int b = m * 16 + hi * 4 + i;
#pragma unroll
                for (int g = 0; g < 4; ++g)
                    gv[m][g][i] = gin[(size_t)b * 1024 + g * 256 + j0 + lo];
            }

        // wait until all 4 peer blocks have h(t) ready (flag >= t+1)
        {
            int need = t + 1;
            for (;;) {
                int ok = 1;
#pragma unroll
                for (int p = 0; p < 4; ++p)
                    ok &= (__hip_atomic_load(&bar[(dir * 4 + p) * 16],
                                             __ATOMIC_RELAXED,
                                             __HIP_MEMORY_SCOPE_AGENT) >= need);
                if (ok) break;
                __builtin_amdgcn_s_sleep(1);
            }
        }

        // h A-fragments: 16 pipelined coherent dwordx4 loads, one drain
        s8v aF[16];
        {
            const uint32* p0 = hr + lo * 128 + hi * 4;
            const uint32* p1 = p0 + 16 * 128;
            asm volatile(
                "global_load_dwordx4 %0, %16, off sc1\n\t"
                "global_load_dwordx4 %1, %16, off offset:64 sc1\n\t"
                "global_load_dwordx4 %2, %16, off offset:128 sc1\n\t"
                "global_load_dwordx4 %3, %16, off offset:192 sc1\n\t"
                "global_load_dwordx4 %4, %16, off offset:256 sc1\n\t"
                "global_load_dwordx4 %5, %16, off offset:320 sc1\n\t"
                "global_load_dwordx4 %6, %16, off offset:384 sc1\n\t"
                "global_load_dwordx4 %7, %16, off offset:448 sc1\n\t"
                "global_load_dwordx4 %8, %17, off sc1\n\t"
                "global_load_dwordx4 %9, %17, off offset:64 sc1\n\t"
                "global_load_dwordx4 %10, %17, off offset:128 sc1\n\t"
                "global_load_dwordx4 %11, %17, off offset:192 sc1\n\t"
                "global_load_dwordx4 %12, %17, off offset:256 sc1\n\t"
                "global_load_dwordx4 %13, %17, off offset:320 sc1\n\t"
                "global_load_dwordx4 %14, %17, off offset:384 sc1\n\t"
                "global_load_dwordx4 %15, %17, off offset:448 sc1\n\t"
                "s_waitcnt vmcnt(0)"
                : "=v"(aF[0]), "=v"(aF[1]), "=v"(aF[2]), "=v"(aF[3]),
                  "=v"(aF[4]), "=v"(aF[5]), "=v"(aF[6]), "=v"(aF[7]),
                  "=v"(aF[8]), "=v"(aF[9]), "=v"(aF[10]), "=v"(aF[11]),
                  "=v"(aF[12]), "=v"(aF[13]), "=v"(aF[14]), "=v"(aF[15])
                : "v"(p0), "v"(p1)
                : "memory");
        }

        f4v acc[2][4];
#pragma unroll
        for (int m = 0; m < 2; ++m)
#pragma unroll
            for (int g = 0; g < 4; ++g) acc[m][g] = (f4v){0.f,0.f,0.f,0.f};
#pragma unroll
        for (int kt = 0; kt < 8; ++kt)
#pragma unroll
            for (int m = 0; m < 2; ++m)
#pragma unroll
                for (int g = 0; g < 4; ++g)
                    acc[m][g] = mfma16(aF[m * 8 + kt], whhF[g][kt], acc[m][g]);

        float hv[2][4];
#pragma unroll
        for (int m = 0; m < 2; ++m)
#pragma unroll
            for (int i = 0; i < 4; ++i) {
                float xi = acc[m][0][i] + gv[m][0][i];
                float xf = acc[m][1][i] + gv[m][1][i];
                float xg = acc[m][2][i] + gv[m][2][i];
                float xo = acc[m][3][i] + gv[m][3][i];
                float c = sigf(xf) * cst[m][i] + sigf(xi) * tanh_(xg);
                cst[m][i] = c;
                float h = sigf(xo) * tanh_(c);
                hv[m][i] = h;
                int b = m * 16 + hi * 4 + i;
                out[((size_t)b * 64 + tp) * 512 + dir * 256 + j0 + lo] = h;
            }

        // pack bf16 pairs across lane-neighbors; even lanes store the dword
#pragma unroll
        for (int m = 0; m < 2; ++m)
#pragma unroll
            for (int i = 0; i < 4; ++i) {
                float o2 = __shfl_xor(hv[m][i], 1);
                if (!(lane & 1)) {
                    uint32 p = (uint32)__bfloat16_as_ushort(__float2bfloat16(hv[m][i]))
                             | ((uint32)__bfloat16_as_ushort(__float2bfloat16(o2)) << 16);
                    int b = m * 16 + hi * 4 + i;
                    __hip_atomic_store(&hw[b * 128 + ((j0 + lo) >> 1)], p,
                                       __ATOMIC_RELAXED, __HIP_MEMORY_SCOPE_AGENT);
                }
            }

        if (t < 63) {
            __syncthreads();   // drains all waves' h stores before flag bump
            if (threadIdx.x == 0)
                __hip_atomic_store(&bar[(dir * 4 + pid) * 16], t + 2,
                                   __ATOMIC_RELAXED, __HIP_MEMORY_SCOPE_AGENT);
        }
    }
}

// ---------------------------------------------------------------------------
// action = max over T of output; action_semantics = action @ fc_W^T + fc_b
// ---------------------------------------------------------------------------
__global__ __launch_bounds__(256) void final_kernel(
    const float* __restrict__ out,   // [32][64][512]
    const float* __restrict__ fcW,   // [300][512]
    const float* __restrict__ fcb,   // [300]
    float* __restrict__ osem)        // [32][300]
{
    int b = blockIdx.x, tid = threadIdx.x;
    __shared__ float act[512];
    for (int h = tid; h < 512; h += 256) {
        float m = -1e30f;
        const float* p = out + (size_t)b * 64 * 512 + h;
#pragma unroll 8
        for (int t = 0; t < 64; ++t) m = fmaxf(m, p[t * 512]);
        act[h] = m;
    }
    __syncthreads();
    int wv = tid >> 6, lane = tid & 63;
    for (int s = wv; s < 300; s += 4) {
        const float* wrow = fcW + (size_t)s * 512 + lane * 8;
        float a = 0.f;
#pragma unroll
        for (int i = 0; i < 8; ++i) a += act[lane * 8 + i] * wrow[i];
#pragma unroll
        for (int off = 32; off; off >>= 1) a += __shfl_xor(a, off);
        if (lane == 0) osem[b * 300 + s] = a + fcb[s];
    }
}

// ---------------------------------------------------------------------------
extern "C" void kernel_launch(void* const* d_in, const int* in_sizes, int n_in,
                              void* d_out, int out_size, void* d_ws, size_t ws_size,
                              hipStream_t stream)
{
    const float* visual  = (const float*)d_in[0];
    const float* objects = (const float*)d_in[1];
    const float* lin_W   = (const float*)d_in[2];
    const float* lin_b   = (const float*)d_in[3];
    const float* W_W     = (const float*)d_in[4];
    const float* W_b     = (const float*)d_in[5];
    const float* U_W     = (const float*)d_in[6];
    const float* U_b     = (const float*)d_in[7];
    const float* b_attn  = (const float*)d_in[8];
    const float* w_W     = (const float*)d_in[9];
    const float* w_b     = (const float*)d_in[10];
    const float* Wih_f   = (const float*)d_in[11];
    const float* Whh_f   = (const float*)d_in[12];
    const float* bih_f   = (const float*)d_in[13];
    const float* bhh_f   = (const float*)d_in[14];
    const float* Wih_b   = (const float*)d_in[15];
    const float* Whh_b   = (const float*)d_in[16];
    const float* bih_b   = (const float*)d_in[17];
    const float* bhh_b   = (const float*)d_in[18];
    const float* fc_W    = (const float*)d_in[19];
    const float* fc_b    = (const float*)d_in[20];

    char* ws = (char*)d_ws;
    size_t o = 0;
    bf16*   feats   = (bf16*)(ws + o);   o += (size_t)2048 * 1024 * 2;   // [BT][1024] bf16
    float*  Wf      = (float*)(ws + o);  o += (size_t)2048 * 512 * 4;    // [BT][512] f32
    float*  Uo      = (float*)(ws + o);  o += (size_t)1152 * 512 * 4;    // [B*36][512] f32
    float*  gatesF  = (float*)(ws + o);  o += (size_t)2048 * 1024 * 4;   // [T][B][1024] f32
    float*  gatesB  = (float*)(ws + o);  o += (size_t)2048 * 1024 * 4;
    uint32* hx      = (uint32*)(ws + o); o += (size_t)2 * 2 * 32 * 128 * 4;
    int*    bar     = (int*)(ws + o);    o += 1024;
    bf16*  visual_b  = (bf16*)(ws + o); o += (size_t)4194304 * 2;
    bf16*  objects_b = (bf16*)(ws + o); o += (size_t)589824 * 2;
    bf16*  lin_Wb    = (bf16*)(ws + o); o += (size_t)1048576 * 2;
    bf16*  W_Wb      = (bf16*)(ws + o); o += (size_t)262144 * 2;
    bf16*  U_Wb      = (bf16*)(ws + o); o += (size_t)262144 * 2;
    bf16*  Wih_fb    = (bf16*)(ws + o); o += (size_t)1048576 * 2;
    bf16*  Whh_fb    = (bf16*)(ws + o); o += (size_t)262144 * 2;
    bf16*  Wih_bb    = (bf16*)(ws + o); o += (size_t)1048576 * 2;
    bf16*  Whh_bb    = (bf16*)(ws + o); o += (size_t)262144 * 2;

    hipMemsetAsync(bar, 0, 1024, stream);

    // fused f32->bf16 conversion (all sizes are multiples of 1024)
    CvtJobs cj;
    const float* srcs[9] = {visual, objects, lin_W, W_W, U_W, Wih_f, Whh_f, Wih_b, Whh_b};
    bf16* dsts[9] = {visual_b, objects_b, lin_Wb, W_Wb, U_Wb, Wih_fb, Whh_fb, Wih_bb, Whh_bb};
    int ns[9] = {4194304, 589824, 1048576, 262144, 262144, 1048576, 262144, 1048576, 262144};
    int acc_b = 0;
    for (int i = 0; i < 9; ++i) {
        cj.src[i] = srcs[i];
        cj.dst[i] = dsts[i];
        cj.start[i] = acc_b;
        acc_b += ns[i] / 1024;
    }
    cj.start[9] = acc_b;

    dim3 blk(256);
    cvt_kernel<<<acc_b, blk, 0, stream>>>(cj);

    // f3d -> feats[:, :512]   (M=2048,N=512,K=2048)
    gemm_bt<bf16><<<256, blk, 0, stream>>>(visual_b, 2048, lin_Wb, lin_b, nullptr,
                                           feats, 1024, 2048, 16, 0);
    // Uo' = objects@U_W^T + (U_b + b_attn)   (M=1152,N=512,K=512)
    gemm_bt<float><<<144, blk, 0, stream>>>(objects_b, 512, U_Wb, U_b, b_attn,
                                            Uo, 512, 512, 16, 0);
    // Wf = f3d@W_W^T + W_b   (M=2048,N=512,K=512)
    gemm_bt<float><<<256, blk, 0, stream>>>(feats, 1024, W_Wb, W_b, nullptr,
                                            Wf, 512, 512, 16, 0);
    // fused attention -> feats[:, 512:]
    attn_kernel<<<2048, blk, 0, stream>>>(Wf, Uo, w_W, w_b, feats);
    // gate input projections -> [T][B][1024] f32   (M=2048,N=1024,K=1024)
    gemm_bt<float><<<512, blk, 0, stream>>>(feats, 1024, Wih_fb, bih_f, bhh_f,
                                            gatesF, 1024, 1024, 32, 1);
    gemm_bt<float><<<512, blk, 0, stream>>>(feats, 1024, Wih_bb, bih_b, bhh_b,
                                            gatesB, 1024, 1024, 32, 1);
    // recurrent BiLSTM -> d_out[0 .. 1048575]
    lstm_kernel<<<8, blk, 0, stream>>>(Whh_fb, Whh_bb, gatesF, gatesB, hx,
                                       (float*)d_out, bar);
    // action max + fc -> d_out[1048576 ..]
    final_kernel<<<32, blk, 0, stream>>>((float*)d_out, fc_W, fc_b,
                                         (float*)d_out + 1048576);
}